// Round 3
// baseline (738.436 us; speedup 1.0000x reference)
//
#include <hip/hip_runtime.h>
#include <cstdint>
#include <cstddef>

#define DM   512
#define SQL  4096
#define NHE  8
#define HDM  64
#define DFF  2048
#define NB   2

typedef unsigned short u16t;
typedef __attribute__((ext_vector_type(8))) __bf16 bf16x8;
typedef __attribute__((ext_vector_type(4))) float f32x4;
typedef __attribute__((ext_vector_type(8))) unsigned short us8;
typedef __attribute__((ext_vector_type(4))) unsigned short us4;
typedef __attribute__((ext_vector_type(4))) short s16x4;

__device__ inline f32x4 mfma16(bf16x8 a, bf16x8 b, f32x4 c) {
    return __builtin_amdgcn_mfma_f32_16x16x32_bf16(a, b, c, 0, 0, 0);
}
// K=16 MFMA: A-operand layout (k = quad*4+j) matches 16x16 C/D row layout, so the
// softmax P-tile feeds PV straight from registers (no LDS round-trip).
__device__ inline f32x4 mfma16k16(s16x4 a, s16x4 b, f32x4 c) {
    return __builtin_amdgcn_mfma_f32_16x16x16bf16_1k(a, b, c, 0, 0, 0);
}

// async global->LDS, 16B per lane; LDS dest = wave-uniform base + lane*16
__device__ inline void load_lds16(const void* g, void* l) {
    __builtin_amdgcn_global_load_lds(
        (const __attribute__((address_space(1))) unsigned int*)g,
        (__attribute__((address_space(3))) unsigned int*)l, 16, 0, 0);
}

__device__ inline u16t f2bf(float x) {
    union { float f; unsigned int u; } v; v.f = x;
    unsigned int r = v.u + 0x7fffu + ((v.u >> 16) & 1u);
    return (u16t)(r >> 16);
}

__device__ inline void store_out(float* C, size_t idx, float v) { C[idx] = v; }
__device__ inline void store_out(u16t* C, size_t idx, float v) { C[idx] = f2bf(v); }

// ---------------- merged fp32->bf16 converts + bias pack + flag init ----------------
__global__ __launch_bounds__(256) void convert_all(
    const float* __restrict__ src, const float* __restrict__ Wq,
    const float* __restrict__ Wk, const float* __restrict__ Wv,
    const float* __restrict__ Wo, const float* __restrict__ W1,
    const float* __restrict__ W2, const float* __restrict__ bq,
    const float* __restrict__ bk, const float* __restrict__ bv,
    u16t* __restrict__ srcbf, u16t* __restrict__ wqkv, u16t* __restrict__ woc,
    u16t* __restrict__ w1c, u16t* __restrict__ w2c,
    float* __restrict__ bqkv, int* __restrict__ flag) {
    const int blk = blockIdx.x;
    const float* s;
    u16t* d;
    int base;
    if (blk < 2048)      { s = src; d = srcbf;           base = blk; }
    else if (blk < 2176) { s = Wq;  d = wqkv;            base = blk - 2048; }
    else if (blk < 2304) { s = Wk;  d = wqkv + 262144;   base = blk - 2176; }
    else if (blk < 2432) { s = Wv;  d = wqkv + 524288;   base = blk - 2304; }
    else if (blk < 2560) { s = Wo;  d = woc;             base = blk - 2432; }
    else if (blk < 3072) { s = W1;  d = w1c;             base = blk - 2560; }
    else if (blk < 3584) { s = W2;  d = w2c;             base = blk - 3072; }
    else {
        for (int i = threadIdx.x; i < 1536; i += 256)
            bqkv[i] = (i < 512) ? bq[i] : (i < 1024 ? bk[i - 512] : bv[i - 1024]);
        if (threadIdx.x == 0) flag[0] = 1;
        return;
    }
    const int i = base * 2048 + threadIdx.x * 8;
    f32x4 a = *(const f32x4*)(s + i);
    f32x4 b = *(const f32x4*)(s + i + 4);
    us8 o;
    o[0] = f2bf(a[0]); o[1] = f2bf(a[1]); o[2] = f2bf(a[2]); o[3] = f2bf(a[3]);
    o[4] = f2bf(b[0]); o[5] = f2bf(b[1]); o[6] = f2bf(b[2]); o[7] = f2bf(b[3]);
    *(us8*)(d + i) = o;
}

// ---------------- mask all-ones check ----------------
__global__ __launch_bounds__(256) void check_mask_k(const f32x4* __restrict__ m, int* flag) {
    const size_t n4 = (size_t)NB * SQL * SQL / 4;
    size_t i = (size_t)blockIdx.x * 256 + threadIdx.x;
    bool bad = false;
    for (; i < n4; i += (size_t)gridDim.x * 256) {
        f32x4 v = m[i];
        bad |= (v[0] != 1.0f) || (v[1] != 1.0f) || (v[2] != 1.0f) || (v[3] != 1.0f);
    }
    if (bad) flag[0] = 0;
}

// ---------------- GEMM: C[M,N] = A[M,K] @ B[N,K]^T + bias, bf16 in, f32 acc --------
template <typename OutT, bool RELU>
__global__ __launch_bounds__(256, 3) void gemm_bt(const u16t* __restrict__ A,
                                                  const u16t* __restrict__ Bw,
                                                  const float* __restrict__ bias,
                                                  OutT* __restrict__ C,
                                                  const int M, const int N, const int K,
                                                  const int ldc) {
    __shared__ u16t As[128 * 32];
    __shared__ u16t Bs[128 * 32];
    const int tid = threadIdx.x;
    const int w = tid >> 6, lane = tid & 63;
    const int l15 = lane & 15, quad = lane >> 4;
    const int m0 = blockIdx.y * 128, n0 = blockIdx.x * 128;
    const int wm = w >> 1, wn = w & 1;

    f32x4 acc[4][4] = {};

    const u16t* Ag = A + ((size_t)(m0 + w * 32 + (lane >> 2))) * K + (lane & 3) * 8;
    const u16t* Bg = Bw + ((size_t)(n0 + w * 32 + (lane >> 2))) * K + (lane & 3) * 8;
    u16t* Asw = &As[(w * 32) * 32];
    u16t* Bsw = &Bs[(w * 32) * 32];

    for (int k0 = 0; k0 < K; k0 += 32) {
        __syncthreads();
        load_lds16(Ag + k0, Asw);
        load_lds16(Ag + (size_t)16 * K + k0, Asw + 16 * 32);
        load_lds16(Bg + k0, Bsw);
        load_lds16(Bg + (size_t)16 * K + k0, Bsw + 16 * 32);
        __syncthreads();
        bf16x8 af[4], bfr[4];
#pragma unroll
        for (int mt = 0; mt < 4; ++mt)
            af[mt] = *(const bf16x8*)&As[(wm * 64 + mt * 16 + l15) * 32 + quad * 8];
#pragma unroll
        for (int nt = 0; nt < 4; ++nt)
            bfr[nt] = *(const bf16x8*)&Bs[(wn * 64 + nt * 16 + l15) * 32 + quad * 8];
#pragma unroll
        for (int mt = 0; mt < 4; ++mt)
#pragma unroll
            for (int nt = 0; nt < 4; ++nt)
                acc[mt][nt] = mfma16(af[mt], bfr[nt], acc[mt][nt]);
    }

    float bv[4];
#pragma unroll
    for (int nt = 0; nt < 4; ++nt) bv[nt] = bias[n0 + wn * 64 + nt * 16 + l15];
#pragma unroll
    for (int mt = 0; mt < 4; ++mt)
#pragma unroll
        for (int r = 0; r < 4; ++r) {
            const int row = m0 + wm * 64 + mt * 16 + quad * 4 + r;
#pragma unroll
            for (int nt = 0; nt < 4; ++nt) {
                float v = acc[mt][nt][r] + bv[nt];
                if (RELU) v = fmaxf(v, 0.0f);
                store_out(C, (size_t)row * ldc + n0 + wn * 64 + nt * 16 + l15, v);
            }
        }
}

// ---------------- V transpose: qkv[b,s,1024+h*64+d] -> vt[(b*8+h)*64+d][s] ----------
__global__ __launch_bounds__(256) void transpose_v(const u16t* __restrict__ qkv,
                                                   u16t* __restrict__ vt) {
    __shared__ u16t t[64 * 72];
    const int sb = blockIdx.x, h = blockIdx.y, b = blockIdx.z;
    const int tid = threadIdx.x;
#pragma unroll
    for (int it = 0; it < 2; ++it) {
        const int idx = it * 256 + tid;
        const int r = idx >> 3, c8 = idx & 7;
        const u16t* gp = qkv + (size_t)(b * SQL + sb * 64 + r) * (3 * DM) + 2 * DM + h * HDM + c8 * 8;
        *(us8*)&t[r * 72 + c8 * 8] = *(const us8*)gp;
    }
    __syncthreads();
#pragma unroll
    for (int it = 0; it < 2; ++it) {
        const int idx = it * 256 + tid;
        const int d = idx >> 3, s8 = idx & 7;
        us8 o;
#pragma unroll
        for (int u = 0; u < 8; ++u) o[u] = t[(s8 * 8 + u) * 72 + d];
        u16t* gp = vt + (size_t)((b * NHE + h) * HDM + d) * SQL + sb * 64 + s8 * 8;
        *(us8*)gp = o;
    }
}

// ---------------- flash attention: S^T via 16x16x32, PV via 16x16x16 (P in regs) ----
// S^T = K.Q^T : C-layout col = token = l15, row = j = quad*4+r  (per 16-tile)
// O  = P.V    : A = P directly from sacc registers (16x16x16 A-layout == C-layout),
//               B = V^T[d][j] b64 reads from swizzled Vs. O rows = tokens quad*4+r.
// Swizzle: logical 16B chunk c of row r lives at physical chunk c ^ (r & 7).
__global__ __launch_bounds__(256, 4) void flash_attn(const u16t* __restrict__ qkv,
                                                     const u16t* __restrict__ vtg,
                                                     const float* __restrict__ mask,
                                                     const int* __restrict__ flag,
                                                     u16t* __restrict__ ctx) {
    __shared__ u16t Ks[128 * 64];        // K[j][d], 8 chunks/row, swizzled
    __shared__ u16t Vs[64 * 128];        // V^T[d][j], 16 chunks/row, swizzled

    const int qt = blockIdx.x, h = blockIdx.y, b = blockIdx.z;
    const int tid = threadIdx.x;
    const int w = tid >> 6, lane = tid & 63;
    const int l15 = lane & 15, quad = lane >> 4;
    const int e3 = l15 & 7;
    const bool allones = (*flag != 0);

    // Q fragments (B-operand of S^T: n = token = l15, k = quad*8+j)
    bf16x8 qf[2][2];
#pragma unroll
    for (int mt = 0; mt < 2; ++mt) {
        const size_t rowb = (size_t)(b * SQL + qt * 128 + w * 32 + mt * 16 + l15) * (3 * DM) + h * HDM;
#pragma unroll
        for (int kk = 0; kk < 2; ++kk)
            qf[mt][kk] = *(const bf16x8*)(qkv + rowb + kk * 32 + quad * 8);
    }

    f32x4 oacc[4][2] = {};               // [dt][mt]; row = token quad*4+r, col = d l15
    float m_r[2] = {-3.0e38f, -3.0e38f};
    float l_r[2] = {0.0f, 0.0f};

    const int r8 = lane >> 3, c8 = lane & 7;     // K staging decomposition
    const int r4 = lane >> 4, c16 = lane & 15;   // V staging decomposition

    for (int kt = 0; kt < SQL / 128; ++kt) {
        const int j0 = kt * 128;
        __syncthreads();
#pragma unroll
        for (int i = 0; i < 4; ++i) {            // K-tile: 8 rows x 8 chunks per iter
            const int row = j0 + w * 32 + i * 8 + r8;
            load_lds16(qkv + (size_t)(b * SQL + row) * (3 * DM) + DM + h * HDM + ((c8 ^ r8) * 8),
                       &Ks[(w * 32 + i * 8) * 64]);
        }
#pragma unroll
        for (int i = 0; i < 4; ++i) {            // V^T tile: 4 d-rows x 16 chunks per iter
            const int d = w * 16 + i * 4 + r4;
            load_lds16(vtg + (size_t)((b * NHE + h) * HDM + d) * SQL + j0 + ((c16 ^ ((i * 4 + r4) & 7)) * 8),
                       &Vs[(w * 16 + i * 4) * 128]);
        }
        __syncthreads();

        // S^T = K . Q^T
        f32x4 sacc[2][8] = {};
#pragma unroll
        for (int kk = 0; kk < 2; ++kk) {
#pragma unroll
            for (int jt = 0; jt < 8; ++jt) {
                bf16x8 af = *(const bf16x8*)&Ks[(jt * 16 + l15) * 64 + (((kk * 4 + quad) ^ e3) * 8)];
                sacc[0][jt] = mfma16(af, qf[0][kk], sacc[0][jt]);
                sacc[1][jt] = mfma16(af, qf[1][kk], sacc[1][jt]);
            }
        }

        // online softmax; scale folded into exp2 argument
        float av[2][4];
#pragma unroll
        for (int mt = 0; mt < 2; ++mt) {
            if (!allones) {
                const int gi = qt * 128 + w * 32 + mt * 16 + l15;
#pragma unroll
                for (int jt = 0; jt < 8; ++jt)
#pragma unroll
                    for (int r = 0; r < 4; ++r) {
                        const int gj = j0 + jt * 16 + quad * 4 + r;
                        sacc[mt][jt][r] = sacc[mt][jt][r] * 0.125f
                                        + (1.0f - mask[((size_t)b * SQL + gi) * SQL + gj]) * (-1.0e9f);
                    }
            }
            float mx = -3.0e38f;
#pragma unroll
            for (int jt = 0; jt < 8; ++jt)
#pragma unroll
                for (int r = 0; r < 4; ++r) mx = fmaxf(mx, sacc[mt][jt][r]);
            mx = fmaxf(mx, __shfl_xor(mx, 16));
            mx = fmaxf(mx, __shfl_xor(mx, 32));
            const float cs = allones ? 0.18033688011112042f : 1.4426950408889634f;
            const float mnew = fmaxf(m_r[mt], mx);
            const float mb = mnew * cs;
            const float alpha = exp2f(fmaf(m_r[mt], cs, -mb));
            m_r[mt] = mnew;
            float rsum = 0.0f;
#pragma unroll
            for (int jt = 0; jt < 8; ++jt)
#pragma unroll
                for (int r = 0; r < 4; ++r) {
                    const float p = exp2f(fmaf(sacc[mt][jt][r], cs, -mb));
                    sacc[mt][jt][r] = p;
                    rsum += p;
                }
            rsum += __shfl_xor(rsum, 16);
            rsum += __shfl_xor(rsum, 32);
            l_r[mt] = l_r[mt] * alpha + rsum;
            // broadcast alpha from softmax lanes (token=l15) to O rows (token=quad*4+r)
#pragma unroll
            for (int r = 0; r < 4; ++r) av[mt][r] = __shfl(alpha, quad * 4 + r);
#pragma unroll
            for (int dt = 0; dt < 4; ++dt)
#pragma unroll
                for (int r = 0; r < 4; ++r) oacc[dt][mt][r] *= av[mt][r];
        }

        // O += P . V  (A = P from registers, B from Vs)
#pragma unroll
        for (int jt = 0; jt < 8; ++jt) {
            s16x4 pa0, pa1;
#pragma unroll
            for (int r = 0; r < 4; ++r) {
                pa0[r] = (short)f2bf(sacc[0][jt][r]);
                pa1[r] = (short)f2bf(sacc[1][jt][r]);
            }
            const int vcol = (((2 * jt + (quad >> 1)) ^ e3) * 8) + (quad & 1) * 4;
#pragma unroll
            for (int dt = 0; dt < 4; ++dt) {
                s16x4 vb = *(const s16x4*)&Vs[(dt * 16 + l15) * 128 + vcol];
                oacc[dt][0] = mfma16k16(pa0, vb, oacc[dt][0]);
                oacc[dt][1] = mfma16k16(pa1, vb, oacc[dt][1]);
            }
        }
    }

    // epilogue: broadcast l to O rows, normalize, store (2B coalesced per 16-lane d-group)
#pragma unroll
    for (int mt = 0; mt < 2; ++mt) {
        float lv[4];
#pragma unroll
        for (int r = 0; r < 4; ++r) lv[r] = __shfl(l_r[mt], quad * 4 + r);
#pragma unroll
        for (int r = 0; r < 4; ++r) {
            const float inv = 1.0f / lv[r];
            const int token = qt * 128 + w * 32 + mt * 16 + quad * 4 + r;
            const size_t base = (size_t)(b * SQL + token) * DM + h * HDM;
#pragma unroll
            for (int dt = 0; dt < 4; ++dt)
                ctx[base + dt * 16 + l15] = f2bf(oacc[dt][mt][r] * inv);
        }
    }
}

// ---------------- fused residual + LayerNorm (one wave per 512-elem row) -----------
template <bool WBF>
__global__ __launch_bounds__(256) void ln_fused(const float* __restrict__ xa,
                                                const float* __restrict__ xb,
                                                const float* __restrict__ g,
                                                const float* __restrict__ be,
                                                float* __restrict__ outf,
                                                u16t* __restrict__ outh) {
    const int row = blockIdx.x * 4 + (threadIdx.x >> 6);
    const int lane = threadIdx.x & 63;
    const size_t base = (size_t)row * DM;
    f32x4 a0 = *(const f32x4*)(xa + base + lane * 4);
    f32x4 b0 = *(const f32x4*)(xb + base + lane * 4);
    f32x4 a1 = *(const f32x4*)(xa + base + 256 + lane * 4);
    f32x4 b1 = *(const f32x4*)(xb + base + 256 + lane * 4);
    f32x4 v0 = a0 + b0, v1 = a1 + b1;
    float s = v0[0] + v0[1] + v0[2] + v0[3] + v1[0] + v1[1] + v1[2] + v1[3];
    float q = v0[0]*v0[0] + v0[1]*v0[1] + v0[2]*v0[2] + v0[3]*v0[3]
            + v1[0]*v1[0] + v1[1]*v1[1] + v1[2]*v1[2] + v1[3]*v1[3];
#pragma unroll
    for (int off = 1; off < 64; off <<= 1) {
        s += __shfl_xor(s, off);
        q += __shfl_xor(q, off);
    }
    const float mean = s * (1.0f / DM);
    const float var = q * (1.0f / DM) - mean * mean;
    const float rs = rsqrtf(var + 1e-5f);
    f32x4 g0 = *(const f32x4*)(g + lane * 4);
    f32x4 g1 = *(const f32x4*)(g + 256 + lane * 4);
    f32x4 e0 = *(const f32x4*)(be + lane * 4);
    f32x4 e1 = *(const f32x4*)(be + 256 + lane * 4);
    f32x4 y0, y1;
#pragma unroll
    for (int i = 0; i < 4; ++i) {
        y0[i] = (v0[i] - mean) * rs * g0[i] + e0[i];
        y1[i] = (v1[i] - mean) * rs * g1[i] + e1[i];
    }
    *(f32x4*)(outf + base + lane * 4) = y0;
    *(f32x4*)(outf + base + 256 + lane * 4) = y1;
    if (WBF) {
        us4 h0, h1;
#pragma unroll
        for (int i = 0; i < 4; ++i) { h0[i] = f2bf(y0[i]); h1[i] = f2bf(y1[i]); }
        *(us4*)(outh + base + lane * 4) = h0;
        *(us4*)(outh + base + 256 + lane * 4) = h1;
    }
}

// ---------------- host ----------------
extern "C" void kernel_launch(void* const* d_in, const int* in_sizes, int n_in,
                              void* d_out, int out_size, void* d_ws, size_t ws_size,
                              hipStream_t stream) {
    const float* src  = (const float*)d_in[0];
    const float* mask = (const float*)d_in[1];
    const float* Wq = (const float*)d_in[2];
    const float* bq = (const float*)d_in[3];
    const float* Wk = (const float*)d_in[4];
    const float* bk = (const float*)d_in[5];
    const float* Wv = (const float*)d_in[6];
    const float* bv = (const float*)d_in[7];
    const float* Wo = (const float*)d_in[8];
    const float* bo = (const float*)d_in[9];
    const float* W1 = (const float*)d_in[10];
    const float* b1 = (const float*)d_in[11];
    const float* W2 = (const float*)d_in[12];
    const float* b2 = (const float*)d_in[13];
    const float* ln1g = (const float*)d_in[14];
    const float* ln1b = (const float*)d_in[15];
    const float* ln2g = (const float*)d_in[16];
    const float* ln2b = (const float*)d_in[17];

    const int M = NB * SQL;  // 8192 tokens

    char* p = (char*)d_ws;
    auto take = [&](size_t bytes) {
        char* r = p;
        p += (bytes + 1023) & ~(size_t)1023;
        return r;
    };
    u16t* regA   = (u16t*)take((size_t)M * DFF * 2);      // qkv [M,1536] then h [M,2048]
    u16t* vtb    = (u16t*)take((size_t)NB * NHE * HDM * SQL * 2);
    u16t* ctxb   = (u16t*)take((size_t)M * DM * 2);
    float* sa_ff = (float*)take((size_t)M * DM * 4);      // sa then ff
    float* x1f   = (float*)take((size_t)M * DM * 4);
    u16t* x1h    = (u16t*)take((size_t)M * DM * 2);
    u16t* srcbf  = (u16t*)take((size_t)M * DM * 2);
    u16t* wqkv   = (u16t*)take((size_t)3 * DM * DM * 2);
    float* bqkv  = (float*)take((size_t)3 * DM * 4);
    u16t* woc    = (u16t*)take((size_t)DM * DM * 2);
    u16t* w1c    = (u16t*)take((size_t)DFF * DM * 2);
    u16t* w2c    = (u16t*)take((size_t)DM * DFF * 2);
    int* flag    = (int*)take(1024);
    u16t* qkvb   = regA;   // [M, 1536]
    u16t* hbuf   = regA;   // [M, 2048] (after flash is done with qkv)

    // all converts + bias pack + flag init in one launch
    convert_all<<<3585, 256, 0, stream>>>(src, Wq, Wk, Wv, Wo, W1, W2, bq, bk, bv,
                                          srcbf, wqkv, woc, w1c, w2c, bqkv, flag);
    // mask all-ones check (flag ordering guaranteed by stream)
    check_mask_k<<<4096, 256, 0, stream>>>((const f32x4*)mask, flag);

    // QKV projection: [8192,512] x [1536,512]^T -> [8192,1536] bf16
    gemm_bt<u16t, false><<<dim3(12, 64), 256, 0, stream>>>(srcbf, wqkv, bqkv, qkvb,
                                                           M, 3 * DM, DM, 3 * DM);
    // V transpose for flash B-operand source
    transpose_v<<<dim3(SQL / 64, NHE, NB), 256, 0, stream>>>(qkvb, vtb);
    // attention
    flash_attn<<<dim3(SQL / 128, NHE, NB), 256, 0, stream>>>(qkvb, vtb, mask, flag, ctxb);
    // out projection -> sa (fp32)
    gemm_bt<float, false><<<dim3(4, 64), 256, 0, stream>>>(ctxb, woc, bo, sa_ff,
                                                           M, DM, DM, DM);
    // x1 = LN(src + sa)  (fp32 + bf16 copies)
    ln_fused<true><<<M / 4, 256, 0, stream>>>(src, sa_ff, ln1g, ln1b, x1f, x1h);
    // FFN1 + ReLU -> h (bf16)
    gemm_bt<u16t, true><<<dim3(16, 64), 256, 0, stream>>>(x1h, w1c, b1, hbuf,
                                                          M, DFF, DM, DFF);
    // FFN2 -> ff (fp32, reuses sa buffer)
    gemm_bt<float, false><<<dim3(4, 64), 256, 0, stream>>>(hbuf, w2c, b2, sa_ff,
                                                           M, DM, DFF, DM);
    // out = LN(x1 + ff)
    ln_fused<false><<<M / 4, 256, 0, stream>>>(x1f, sa_ff, ln2g, ln2b, (float*)d_out,
                                               (u16t*)nullptr);
}

// Round 4
// 518.118 us; speedup vs baseline: 1.4252x; 1.4252x over previous
//
#include <hip/hip_runtime.h>
#include <cstdint>
#include <cstddef>

#define DM   512
#define SQL  4096
#define NHE  8
#define HDM  64
#define DFF  2048
#define NB   2

typedef unsigned short u16t;
typedef __attribute__((ext_vector_type(8))) __bf16 bf16x8;
typedef __attribute__((ext_vector_type(4))) float f32x4;
typedef __attribute__((ext_vector_type(8))) unsigned short us8;
typedef __attribute__((ext_vector_type(4))) unsigned short us4;
typedef __attribute__((ext_vector_type(4))) short s16x4;

__device__ inline f32x4 mfma16(bf16x8 a, bf16x8 b, f32x4 c) {
    return __builtin_amdgcn_mfma_f32_16x16x32_bf16(a, b, c, 0, 0, 0);
}
// K=16 MFMA: A-operand layout (k = quad*4+j) matches 16x16 C/D row layout, so the
// softmax P-tile feeds PV straight from registers (no LDS round-trip).
__device__ inline f32x4 mfma16k16(s16x4 a, s16x4 b, f32x4 c) {
    return __builtin_amdgcn_mfma_f32_16x16x16bf16_1k(a, b, c, 0, 0, 0);
}

// async global->LDS, 16B per lane; LDS dest = wave-uniform base + lane*16
__device__ inline void load_lds16(const void* g, void* l) {
    __builtin_amdgcn_global_load_lds(
        (const __attribute__((address_space(1))) unsigned int*)g,
        (__attribute__((address_space(3))) unsigned int*)l, 16, 0, 0);
}

__device__ inline u16t f2bf(float x) {
    union { float f; unsigned int u; } v; v.f = x;
    unsigned int r = v.u + 0x7fffu + ((v.u >> 16) & 1u);
    return (u16t)(r >> 16);
}

__device__ inline void store_out(float* C, size_t idx, float v) { C[idx] = v; }
__device__ inline void store_out(u16t* C, size_t idx, float v) { C[idx] = f2bf(v); }

// ---------------- merged fp32->bf16 converts + bias pack + flag init ----------------
__global__ __launch_bounds__(256) void convert_all(
    const float* __restrict__ src, const float* __restrict__ Wq,
    const float* __restrict__ Wk, const float* __restrict__ Wv,
    const float* __restrict__ Wo, const float* __restrict__ W1,
    const float* __restrict__ W2, const float* __restrict__ bq,
    const float* __restrict__ bk, const float* __restrict__ bv,
    u16t* __restrict__ srcbf, u16t* __restrict__ wqkv, u16t* __restrict__ woc,
    u16t* __restrict__ w1c, u16t* __restrict__ w2c,
    float* __restrict__ bqkv, int* __restrict__ flag) {
    const int blk = blockIdx.x;
    const float* s;
    u16t* d;
    int base;
    if (blk < 2048)      { s = src; d = srcbf;           base = blk; }
    else if (blk < 2176) { s = Wq;  d = wqkv;            base = blk - 2048; }
    else if (blk < 2304) { s = Wk;  d = wqkv + 262144;   base = blk - 2176; }
    else if (blk < 2432) { s = Wv;  d = wqkv + 524288;   base = blk - 2304; }
    else if (blk < 2560) { s = Wo;  d = woc;             base = blk - 2432; }
    else if (blk < 3072) { s = W1;  d = w1c;             base = blk - 2560; }
    else if (blk < 3584) { s = W2;  d = w2c;             base = blk - 3072; }
    else {
        for (int i = threadIdx.x; i < 1536; i += 256)
            bqkv[i] = (i < 512) ? bq[i] : (i < 1024 ? bk[i - 512] : bv[i - 1024]);
        if (threadIdx.x == 0) flag[0] = 1;
        return;
    }
    const int i = base * 2048 + threadIdx.x * 8;
    f32x4 a = *(const f32x4*)(s + i);
    f32x4 b = *(const f32x4*)(s + i + 4);
    us8 o;
    o[0] = f2bf(a[0]); o[1] = f2bf(a[1]); o[2] = f2bf(a[2]); o[3] = f2bf(a[3]);
    o[4] = f2bf(b[0]); o[5] = f2bf(b[1]); o[6] = f2bf(b[2]); o[7] = f2bf(b[3]);
    *(us8*)(d + i) = o;
}

// ---------------- mask all-ones check ----------------
__global__ __launch_bounds__(256) void check_mask_k(const f32x4* __restrict__ m, int* flag) {
    const size_t n4 = (size_t)NB * SQL * SQL / 4;
    size_t i = (size_t)blockIdx.x * 256 + threadIdx.x;
    bool bad = false;
    for (; i < n4; i += (size_t)gridDim.x * 256) {
        f32x4 v = m[i];
        bad |= (v[0] != 1.0f) || (v[1] != 1.0f) || (v[2] != 1.0f) || (v[3] != 1.0f);
    }
    if (bad) flag[0] = 0;
}

// ---------------- GEMM: C[M,N] = A[M,K] @ B[N,K]^T + bias, bf16 in, f32 acc --------
template <typename OutT, bool RELU>
__global__ __launch_bounds__(256, 3) void gemm_bt(const u16t* __restrict__ A,
                                                  const u16t* __restrict__ Bw,
                                                  const float* __restrict__ bias,
                                                  OutT* __restrict__ C,
                                                  const int M, const int N, const int K,
                                                  const int ldc) {
    __shared__ u16t As[128 * 32];
    __shared__ u16t Bs[128 * 32];
    const int tid = threadIdx.x;
    const int w = tid >> 6, lane = tid & 63;
    const int l15 = lane & 15, quad = lane >> 4;
    const int m0 = blockIdx.y * 128, n0 = blockIdx.x * 128;
    const int wm = w >> 1, wn = w & 1;

    f32x4 acc[4][4] = {};

    const u16t* Ag = A + ((size_t)(m0 + w * 32 + (lane >> 2))) * K + (lane & 3) * 8;
    const u16t* Bg = Bw + ((size_t)(n0 + w * 32 + (lane >> 2))) * K + (lane & 3) * 8;
    u16t* Asw = &As[(w * 32) * 32];
    u16t* Bsw = &Bs[(w * 32) * 32];

    for (int k0 = 0; k0 < K; k0 += 32) {
        __syncthreads();
        load_lds16(Ag + k0, Asw);
        load_lds16(Ag + (size_t)16 * K + k0, Asw + 16 * 32);
        load_lds16(Bg + k0, Bsw);
        load_lds16(Bg + (size_t)16 * K + k0, Bsw + 16 * 32);
        __syncthreads();
        bf16x8 af[4], bfr[4];
#pragma unroll
        for (int mt = 0; mt < 4; ++mt)
            af[mt] = *(const bf16x8*)&As[(wm * 64 + mt * 16 + l15) * 32 + quad * 8];
#pragma unroll
        for (int nt = 0; nt < 4; ++nt)
            bfr[nt] = *(const bf16x8*)&Bs[(wn * 64 + nt * 16 + l15) * 32 + quad * 8];
#pragma unroll
        for (int mt = 0; mt < 4; ++mt)
#pragma unroll
            for (int nt = 0; nt < 4; ++nt)
                acc[mt][nt] = mfma16(af[mt], bfr[nt], acc[mt][nt]);
    }

    float bv[4];
#pragma unroll
    for (int nt = 0; nt < 4; ++nt) bv[nt] = bias[n0 + wn * 64 + nt * 16 + l15];
#pragma unroll
    for (int mt = 0; mt < 4; ++mt)
#pragma unroll
        for (int r = 0; r < 4; ++r) {
            const int row = m0 + wm * 64 + mt * 16 + quad * 4 + r;
#pragma unroll
            for (int nt = 0; nt < 4; ++nt) {
                float v = acc[mt][nt][r] + bv[nt];
                if (RELU) v = fmaxf(v, 0.0f);
                store_out(C, (size_t)row * ldc + n0 + wn * 64 + nt * 16 + l15, v);
            }
        }
}

// ---------------- V transpose: qkv[b,s,1024+h*64+d] -> vt[(b*8+h)*64+d][s] ----------
__global__ __launch_bounds__(256) void transpose_v(const u16t* __restrict__ qkv,
                                                   u16t* __restrict__ vt) {
    __shared__ u16t t[64 * 72];
    const int sb = blockIdx.x, h = blockIdx.y, b = blockIdx.z;
    const int tid = threadIdx.x;
#pragma unroll
    for (int it = 0; it < 2; ++it) {
        const int idx = it * 256 + tid;
        const int r = idx >> 3, c8 = idx & 7;
        const u16t* gp = qkv + (size_t)(b * SQL + sb * 64 + r) * (3 * DM) + 2 * DM + h * HDM + c8 * 8;
        *(us8*)&t[r * 72 + c8 * 8] = *(const us8*)gp;
    }
    __syncthreads();
#pragma unroll
    for (int it = 0; it < 2; ++it) {
        const int idx = it * 256 + tid;
        const int d = idx >> 3, s8 = idx & 7;
        us8 o;
#pragma unroll
        for (int u = 0; u < 8; ++u) o[u] = t[(s8 * 8 + u) * 72 + d];
        u16t* gp = vt + (size_t)((b * NHE + h) * HDM + d) * SQL + sb * 64 + s8 * 8;
        *(us8*)gp = o;
    }
}

// ---------------- flash attention: S^T via 16x16x32, PV via 16x16x16 (P in regs) ----
// S^T = K.Q^T : C-layout col = token = l15, row = j = quad*4+r  (per 16-tile)
// O  = P.V    : A = P directly from sacc registers (16x16x16 A-layout == C-layout),
//               B = V^T[d][j] b64 reads from swizzled Vs. O rows = tokens quad*4+r.
// Swizzle: logical 16B chunk c of row r lives at physical chunk c ^ (r & 7).
// NOTE launch_bounds(256, 2): design needs ~150 VGPRs (sacc 64 + oacc 32 + qf 16);
// (256,4) caps at 64 VGPRs -> 743 MB scratch spill, 2.7x regression (round 3).
__global__ __launch_bounds__(256, 2) void flash_attn(const u16t* __restrict__ qkv,
                                                     const u16t* __restrict__ vtg,
                                                     const float* __restrict__ mask,
                                                     const int* __restrict__ flag,
                                                     u16t* __restrict__ ctx) {
    __shared__ u16t Ks[128 * 64];        // K[j][d], 8 chunks/row, swizzled
    __shared__ u16t Vs[64 * 128];        // V^T[d][j], 16 chunks/row, swizzled

    const int qt = blockIdx.x, h = blockIdx.y, b = blockIdx.z;
    const int tid = threadIdx.x;
    const int w = tid >> 6, lane = tid & 63;
    const int l15 = lane & 15, quad = lane >> 4;
    const int e3 = l15 & 7;
    const bool allones = (*flag != 0);

    // Q fragments (B-operand of S^T: n = token = l15, k = quad*8+j)
    bf16x8 qf[2][2];
#pragma unroll
    for (int mt = 0; mt < 2; ++mt) {
        const size_t rowb = (size_t)(b * SQL + qt * 128 + w * 32 + mt * 16 + l15) * (3 * DM) + h * HDM;
#pragma unroll
        for (int kk = 0; kk < 2; ++kk)
            qf[mt][kk] = *(const bf16x8*)(qkv + rowb + kk * 32 + quad * 8);
    }

    f32x4 oacc[4][2] = {};               // [dt][mt]; row = token quad*4+r, col = d l15
    float m_r[2] = {-3.0e38f, -3.0e38f};
    float l_r[2] = {0.0f, 0.0f};

    const int r8 = lane >> 3, c8 = lane & 7;     // K staging decomposition
    const int r4 = lane >> 4, c16 = lane & 15;   // V staging decomposition

    for (int kt = 0; kt < SQL / 128; ++kt) {
        const int j0 = kt * 128;
        __syncthreads();
#pragma unroll
        for (int i = 0; i < 4; ++i) {            // K-tile: 8 rows x 8 chunks per iter
            const int row = j0 + w * 32 + i * 8 + r8;
            load_lds16(qkv + (size_t)(b * SQL + row) * (3 * DM) + DM + h * HDM + ((c8 ^ r8) * 8),
                       &Ks[(w * 32 + i * 8) * 64]);
        }
#pragma unroll
        for (int i = 0; i < 4; ++i) {            // V^T tile: 4 d-rows x 16 chunks per iter
            const int d = w * 16 + i * 4 + r4;
            load_lds16(vtg + (size_t)((b * NHE + h) * HDM + d) * SQL + j0 + ((c16 ^ ((i * 4 + r4) & 7)) * 8),
                       &Vs[(w * 16 + i * 4) * 128]);
        }
        __syncthreads();

        // S^T = K . Q^T
        f32x4 sacc[2][8] = {};
#pragma unroll
        for (int kk = 0; kk < 2; ++kk) {
#pragma unroll
            for (int jt = 0; jt < 8; ++jt) {
                bf16x8 af = *(const bf16x8*)&Ks[(jt * 16 + l15) * 64 + (((kk * 4 + quad) ^ e3) * 8)];
                sacc[0][jt] = mfma16(af, qf[0][kk], sacc[0][jt]);
                sacc[1][jt] = mfma16(af, qf[1][kk], sacc[1][jt]);
            }
        }

        // online softmax; scale folded into exp2 argument
        float av[2][4];
#pragma unroll
        for (int mt = 0; mt < 2; ++mt) {
            if (!allones) {
                const int gi = qt * 128 + w * 32 + mt * 16 + l15;
#pragma unroll
                for (int jt = 0; jt < 8; ++jt)
#pragma unroll
                    for (int r = 0; r < 4; ++r) {
                        const int gj = j0 + jt * 16 + quad * 4 + r;
                        sacc[mt][jt][r] = sacc[mt][jt][r] * 0.125f
                                        + (1.0f - mask[((size_t)b * SQL + gi) * SQL + gj]) * (-1.0e9f);
                    }
            }
            float mx = -3.0e38f;
#pragma unroll
            for (int jt = 0; jt < 8; ++jt)
#pragma unroll
                for (int r = 0; r < 4; ++r) mx = fmaxf(mx, sacc[mt][jt][r]);
            mx = fmaxf(mx, __shfl_xor(mx, 16));
            mx = fmaxf(mx, __shfl_xor(mx, 32));
            const float cs = allones ? 0.18033688011112042f : 1.4426950408889634f;
            const float mnew = fmaxf(m_r[mt], mx);
            const float mb = mnew * cs;
            const float alpha = exp2f(fmaf(m_r[mt], cs, -mb));
            m_r[mt] = mnew;
            float rsum = 0.0f;
#pragma unroll
            for (int jt = 0; jt < 8; ++jt)
#pragma unroll
                for (int r = 0; r < 4; ++r) {
                    const float p = exp2f(fmaf(sacc[mt][jt][r], cs, -mb));
                    sacc[mt][jt][r] = p;
                    rsum += p;
                }
            rsum += __shfl_xor(rsum, 16);
            rsum += __shfl_xor(rsum, 32);
            l_r[mt] = l_r[mt] * alpha + rsum;
            // broadcast alpha from softmax lanes (token=l15) to O rows (token=quad*4+r)
#pragma unroll
            for (int r = 0; r < 4; ++r) av[mt][r] = __shfl(alpha, quad * 4 + r);
#pragma unroll
            for (int dt = 0; dt < 4; ++dt)
#pragma unroll
                for (int r = 0; r < 4; ++r) oacc[dt][mt][r] *= av[mt][r];
        }

        // O += P . V  (A = P from registers, B from Vs)
#pragma unroll
        for (int jt = 0; jt < 8; ++jt) {
            s16x4 pa0, pa1;
#pragma unroll
            for (int r = 0; r < 4; ++r) {
                pa0[r] = (short)f2bf(sacc[0][jt][r]);
                pa1[r] = (short)f2bf(sacc[1][jt][r]);
            }
            const int vcol = (((2 * jt + (quad >> 1)) ^ e3) * 8) + (quad & 1) * 4;
#pragma unroll
            for (int dt = 0; dt < 4; ++dt) {
                s16x4 vb = *(const s16x4*)&Vs[(dt * 16 + l15) * 128 + vcol];
                oacc[dt][0] = mfma16k16(pa0, vb, oacc[dt][0]);
                oacc[dt][1] = mfma16k16(pa1, vb, oacc[dt][1]);
            }
        }
    }

    // epilogue: broadcast l to O rows, normalize, store (2B coalesced per 16-lane d-group)
#pragma unroll
    for (int mt = 0; mt < 2; ++mt) {
        float lv[4];
#pragma unroll
        for (int r = 0; r < 4; ++r) lv[r] = __shfl(l_r[mt], quad * 4 + r);
#pragma unroll
        for (int r = 0; r < 4; ++r) {
            const float inv = 1.0f / lv[r];
            const int token = qt * 128 + w * 32 + mt * 16 + quad * 4 + r;
            const size_t base = (size_t)(b * SQL + token) * DM + h * HDM;
#pragma unroll
            for (int dt = 0; dt < 4; ++dt)
                ctx[base + dt * 16 + l15] = f2bf(oacc[dt][mt][r] * inv);
        }
    }
}

// ---------------- fused residual + LayerNorm (one wave per 512-elem row) -----------
template <bool WBF>
__global__ __launch_bounds__(256) void ln_fused(const float* __restrict__ xa,
                                                const float* __restrict__ xb,
                                                const float* __restrict__ g,
                                                const float* __restrict__ be,
                                                float* __restrict__ outf,
                                                u16t* __restrict__ outh) {
    const int row = blockIdx.x * 4 + (threadIdx.x >> 6);
    const int lane = threadIdx.x & 63;
    const size_t base = (size_t)row * DM;
    f32x4 a0 = *(const f32x4*)(xa + base + lane * 4);
    f32x4 b0 = *(const f32x4*)(xb + base + lane * 4);
    f32x4 a1 = *(const f32x4*)(xa + base + 256 + lane * 4);
    f32x4 b1 = *(const f32x4*)(xb + base + 256 + lane * 4);
    f32x4 v0 = a0 + b0, v1 = a1 + b1;
    float s = v0[0] + v0[1] + v0[2] + v0[3] + v1[0] + v1[1] + v1[2] + v1[3];
    float q = v0[0]*v0[0] + v0[1]*v0[1] + v0[2]*v0[2] + v0[3]*v0[3]
            + v1[0]*v1[0] + v1[1]*v1[1] + v1[2]*v1[2] + v1[3]*v1[3];
#pragma unroll
    for (int off = 1; off < 64; off <<= 1) {
        s += __shfl_xor(s, off);
        q += __shfl_xor(q, off);
    }
    const float mean = s * (1.0f / DM);
    const float var = q * (1.0f / DM) - mean * mean;
    const float rs = rsqrtf(var + 1e-5f);
    f32x4 g0 = *(const f32x4*)(g + lane * 4);
    f32x4 g1 = *(const f32x4*)(g + 256 + lane * 4);
    f32x4 e0 = *(const f32x4*)(be + lane * 4);
    f32x4 e1 = *(const f32x4*)(be + 256 + lane * 4);
    f32x4 y0, y1;
#pragma unroll
    for (int i = 0; i < 4; ++i) {
        y0[i] = (v0[i] - mean) * rs * g0[i] + e0[i];
        y1[i] = (v1[i] - mean) * rs * g1[i] + e1[i];
    }
    *(f32x4*)(outf + base + lane * 4) = y0;
    *(f32x4*)(outf + base + 256 + lane * 4) = y1;
    if (WBF) {
        us4 h0, h1;
#pragma unroll
        for (int i = 0; i < 4; ++i) { h0[i] = f2bf(y0[i]); h1[i] = f2bf(y1[i]); }
        *(us4*)(outh + base + lane * 4) = h0;
        *(us4*)(outh + base + 256 + lane * 4) = h1;
    }
}

// ---------------- host ----------------
extern "C" void kernel_launch(void* const* d_in, const int* in_sizes, int n_in,
                              void* d_out, int out_size, void* d_ws, size_t ws_size,
                              hipStream_t stream) {
    const float* src  = (const float*)d_in[0];
    const float* mask = (const float*)d_in[1];
    const float* Wq = (const float*)d_in[2];
    const float* bq = (const float*)d_in[3];
    const float* Wk = (const float*)d_in[4];
    const float* bk = (const float*)d_in[5];
    const float* Wv = (const float*)d_in[6];
    const float* bv = (const float*)d_in[7];
    const float* Wo = (const float*)d_in[8];
    const float* bo = (const float*)d_in[9];
    const float* W1 = (const float*)d_in[10];
    const float* b1 = (const float*)d_in[11];
    const float* W2 = (const float*)d_in[12];
    const float* b2 = (const float*)d_in[13];
    const float* ln1g = (const float*)d_in[14];
    const float* ln1b = (const float*)d_in[15];
    const float* ln2g = (const float*)d_in[16];
    const float* ln2b = (const float*)d_in[17];

    const int M = NB * SQL;  // 8192 tokens

    char* p = (char*)d_ws;
    auto take = [&](size_t bytes) {
        char* r = p;
        p += (bytes + 1023) & ~(size_t)1023;
        return r;
    };
    u16t* regA   = (u16t*)take((size_t)M * DFF * 2);      // qkv [M,1536] then h [M,2048]
    u16t* vtb    = (u16t*)take((size_t)NB * NHE * HDM * SQL * 2);
    u16t* ctxb   = (u16t*)take((size_t)M * DM * 2);
    float* sa_ff = (float*)take((size_t)M * DM * 4);      // sa then ff
    float* x1f   = (float*)take((size_t)M * DM * 4);
    u16t* x1h    = (u16t*)take((size_t)M * DM * 2);
    u16t* srcbf  = (u16t*)take((size_t)M * DM * 2);
    u16t* wqkv   = (u16t*)take((size_t)3 * DM * DM * 2);
    float* bqkv  = (float*)take((size_t)3 * DM * 4);
    u16t* woc    = (u16t*)take((size_t)DM * DM * 2);
    u16t* w1c    = (u16t*)take((size_t)DFF * DM * 2);
    u16t* w2c    = (u16t*)take((size_t)DM * DFF * 2);
    int* flag    = (int*)take(1024);
    u16t* qkvb   = regA;   // [M, 1536]
    u16t* hbuf   = regA;   // [M, 2048] (after flash is done with qkv)

    // all converts + bias pack + flag init in one launch
    convert_all<<<3585, 256, 0, stream>>>(src, Wq, Wk, Wv, Wo, W1, W2, bq, bk, bv,
                                          srcbf, wqkv, woc, w1c, w2c, bqkv, flag);
    // mask all-ones check (flag ordering guaranteed by stream)
    check_mask_k<<<4096, 256, 0, stream>>>((const f32x4*)mask, flag);

    // QKV projection: [8192,512] x [1536,512]^T -> [8192,1536] bf16
    gemm_bt<u16t, false><<<dim3(12, 64), 256, 0, stream>>>(srcbf, wqkv, bqkv, qkvb,
                                                           M, 3 * DM, DM, 3 * DM);
    // V transpose for flash B-operand source
    transpose_v<<<dim3(SQL / 64, NHE, NB), 256, 0, stream>>>(qkvb, vtb);
    // attention
    flash_attn<<<dim3(SQL / 128, NHE, NB), 256, 0, stream>>>(qkvb, vtb, mask, flag, ctxb);
    // out projection -> sa (fp32)
    gemm_bt<float, false><<<dim3(4, 64), 256, 0, stream>>>(ctxb, woc, bo, sa_ff,
                                                           M, DM, DM, DM);
    // x1 = LN(src + sa)  (fp32 + bf16 copies)
    ln_fused<true><<<M / 4, 256, 0, stream>>>(src, sa_ff, ln1g, ln1b, x1f, x1h);
    // FFN1 + ReLU -> h (bf16)
    gemm_bt<u16t, true><<<dim3(16, 64), 256, 0, stream>>>(x1h, w1c, b1, hbuf,
                                                          M, DFF, DM, DFF);
    // FFN2 -> ff (fp32, reuses sa buffer)
    gemm_bt<float, false><<<dim3(4, 64), 256, 0, stream>>>(hbuf, w2c, b2, sa_ff,
                                                           M, DM, DFF, DM);
    // out = LN(x1 + ff)
    ln_fused<false><<<M / 4, 256, 0, stream>>>(x1f, sa_ff, ln2g, ln2b, (float*)d_out,
                                               (u16t*)nullptr);
}

// Round 5
// 471.367 us; speedup vs baseline: 1.5666x; 1.0992x over previous
//
#include <hip/hip_runtime.h>
#include <cstdint>
#include <cstddef>

#define DM   512
#define SQL  4096
#define NHE  8
#define HDM  64
#define DFF  2048
#define NB   2

typedef unsigned short u16t;
typedef __attribute__((ext_vector_type(8))) __bf16 bf16x8;
typedef __attribute__((ext_vector_type(4))) float f32x4;
typedef __attribute__((ext_vector_type(8))) unsigned short us8;
typedef __attribute__((ext_vector_type(4))) unsigned short us4;
typedef __attribute__((ext_vector_type(4))) short s16x4;

extern "C" __device__ float __ocml_native_exp2_f32(float);  // one v_exp_f32
__device__ inline float ex2(float x) { return __ocml_native_exp2_f32(x); }

__device__ inline f32x4 mfma16(bf16x8 a, bf16x8 b, f32x4 c) {
    return __builtin_amdgcn_mfma_f32_16x16x32_bf16(a, b, c, 0, 0, 0);
}
// K=16 MFMA: A-operand layout (k = quad*4+j) matches 16x16 C/D row layout, so the
// softmax P-tile feeds PV straight from registers (no LDS round-trip).
__device__ inline f32x4 mfma16k16(s16x4 a, s16x4 b, f32x4 c) {
    return __builtin_amdgcn_mfma_f32_16x16x16bf16_1k(a, b, c, 0, 0, 0);
}

// async global->LDS, 16B per lane; LDS dest = wave-uniform base + lane*16
__device__ inline void load_lds16(const void* g, void* l) {
    __builtin_amdgcn_global_load_lds(
        (const __attribute__((address_space(1))) unsigned int*)g,
        (__attribute__((address_space(3))) unsigned int*)l, 16, 0, 0);
}

__device__ inline u16t f2bf(float x) {
    union { float f; unsigned int u; } v; v.f = x;
    unsigned int r = v.u + 0x7fffu + ((v.u >> 16) & 1u);
    return (u16t)(r >> 16);
}

// pack 2 f32 -> 2 bf16 (round-half-up) in one u32: 2 adds + 1 v_perm_b32
__device__ inline unsigned int pk_bf2(float lo, float hi) {
    union { float f; unsigned int u; } a, b;
    a.f = lo; b.f = hi;
    return __builtin_amdgcn_perm(b.u + 0x8000u, a.u + 0x8000u, 0x07060302u);
}

__device__ inline void store_out(float* C, size_t idx, float v) { C[idx] = v; }
__device__ inline void store_out(u16t* C, size_t idx, float v) { C[idx] = f2bf(v); }

// ------- merged fp32->bf16 converts + bias pack + mask all-ones check --------------
// flag semantics: flag[0] == 42 means "mask is NOT all ones" (order-free; works with
// 0xAA poison; if flag is garbage==42 the slow-but-correct mask path runs).
__global__ __launch_bounds__(256) void convert_all(
    const float* __restrict__ src, const float* __restrict__ Wq,
    const float* __restrict__ Wk, const float* __restrict__ Wv,
    const float* __restrict__ Wo, const float* __restrict__ W1,
    const float* __restrict__ W2, const float* __restrict__ bq,
    const float* __restrict__ bk, const float* __restrict__ bv,
    const f32x4* __restrict__ mask4,
    u16t* __restrict__ srcbf, u16t* __restrict__ wqkv, u16t* __restrict__ woc,
    u16t* __restrict__ w1c, u16t* __restrict__ w2c,
    float* __restrict__ bqkv, int* __restrict__ flag) {
    const int blk = blockIdx.x;
    const float* s;
    u16t* d;
    int base;
    if (blk < 2048)      { s = src; d = srcbf;           base = blk; }
    else if (blk < 2176) { s = Wq;  d = wqkv;            base = blk - 2048; }
    else if (blk < 2304) { s = Wk;  d = wqkv + 262144;   base = blk - 2176; }
    else if (blk < 2432) { s = Wv;  d = wqkv + 524288;   base = blk - 2304; }
    else if (blk < 2560) { s = Wo;  d = woc;             base = blk - 2432; }
    else if (blk < 3072) { s = W1;  d = w1c;             base = blk - 2560; }
    else if (blk < 3584) { s = W2;  d = w2c;             base = blk - 3072; }
    else if (blk == 3584) {
        for (int i = threadIdx.x; i < 1536; i += 256)
            bqkv[i] = (i < 512) ? bq[i] : (i < 1024 ? bk[i - 512] : bv[i - 1024]);
        return;
    } else {
        // mask all-ones check over 2048 blocks
        const size_t n4 = (size_t)NB * SQL * SQL / 4;
        size_t i = (size_t)(blk - 3585) * 256 + threadIdx.x;
        bool bad = false;
        for (; i < n4; i += (size_t)2048 * 256) {
            f32x4 v = mask4[i];
            bad |= (v[0] != 1.0f) || (v[1] != 1.0f) || (v[2] != 1.0f) || (v[3] != 1.0f);
        }
        if (bad) flag[0] = 42;
        return;
    }
    const int i = base * 2048 + threadIdx.x * 8;
    f32x4 a = *(const f32x4*)(s + i);
    f32x4 b = *(const f32x4*)(s + i + 4);
    us8 o;
    o[0] = f2bf(a[0]); o[1] = f2bf(a[1]); o[2] = f2bf(a[2]); o[3] = f2bf(a[3]);
    o[4] = f2bf(b[0]); o[5] = f2bf(b[1]); o[6] = f2bf(b[2]); o[7] = f2bf(b[3]);
    *(us8*)(d + i) = o;
}

// ---------------- GEMM: C[M,N] = A[M,K] @ B[N,K]^T + bias, bf16 in, f32 acc --------
// 128M x BN tile, BK=32, 4 waves as 2x2; BN=128 for wide-N, BN=64 doubles grid for
// narrow-N (N=512 at BN=128 gives 256 blocks = 1 block/CU -> barrier-exposed).
template <typename OutT, bool RELU, int BN>
__global__ __launch_bounds__(256, 3) void gemm_bt(const u16t* __restrict__ A,
                                                  const u16t* __restrict__ Bw,
                                                  const float* __restrict__ bias,
                                                  OutT* __restrict__ C,
                                                  const int M, const int N, const int K,
                                                  const int ldc) {
    __shared__ u16t As[128 * 32];
    __shared__ u16t Bs[BN * 32];
    constexpr int NT = BN / 32;          // n-subtiles per wave
    const int tid = threadIdx.x;
    const int w = tid >> 6, lane = tid & 63;
    const int l15 = lane & 15, quad = lane >> 4;
    const int m0 = blockIdx.y * 128, n0 = blockIdx.x * BN;
    const int wm = w >> 1, wn = w & 1;

    f32x4 acc[4][NT] = {};

    const u16t* Ag = A + ((size_t)(m0 + w * 32 + (lane >> 2))) * K + (lane & 3) * 8;
    const u16t* Bg = Bw + ((size_t)(n0 + w * (BN / 4) + (lane >> 2))) * K + (lane & 3) * 8;
    u16t* Asw = &As[(w * 32) * 32];
    u16t* Bsw = &Bs[(w * (BN / 4)) * 32];

    for (int k0 = 0; k0 < K; k0 += 32) {
        __syncthreads();
        load_lds16(Ag + k0, Asw);
        load_lds16(Ag + (size_t)16 * K + k0, Asw + 16 * 32);
#pragma unroll
        for (int i = 0; i < BN / 64; ++i)
            load_lds16(Bg + (size_t)(16 * i) * K + k0, Bsw + i * 16 * 32);
        __syncthreads();
        bf16x8 af[4], bfr[NT];
#pragma unroll
        for (int mt = 0; mt < 4; ++mt)
            af[mt] = *(const bf16x8*)&As[(wm * 64 + mt * 16 + l15) * 32 + quad * 8];
#pragma unroll
        for (int nt = 0; nt < NT; ++nt)
            bfr[nt] = *(const bf16x8*)&Bs[(wn * (BN / 2) + nt * 16 + l15) * 32 + quad * 8];
#pragma unroll
        for (int mt = 0; mt < 4; ++mt)
#pragma unroll
            for (int nt = 0; nt < NT; ++nt)
                acc[mt][nt] = mfma16(af[mt], bfr[nt], acc[mt][nt]);
    }

    float bv[NT];
#pragma unroll
    for (int nt = 0; nt < NT; ++nt) bv[nt] = bias[n0 + wn * (BN / 2) + nt * 16 + l15];
#pragma unroll
    for (int mt = 0; mt < 4; ++mt)
#pragma unroll
        for (int r = 0; r < 4; ++r) {
            const int row = m0 + wm * 64 + mt * 16 + quad * 4 + r;
#pragma unroll
            for (int nt = 0; nt < NT; ++nt) {
                float v = acc[mt][nt][r] + bv[nt];
                if (RELU) v = fmaxf(v, 0.0f);
                store_out(C, (size_t)row * ldc + n0 + wn * (BN / 2) + nt * 16 + l15, v);
            }
        }
}

// ---------------- V transpose: qkv[b,s,1024+h*64+d] -> vt[(b*8+h)*64+d][s] ----------
__global__ __launch_bounds__(256) void transpose_v(const u16t* __restrict__ qkv,
                                                   u16t* __restrict__ vt) {
    __shared__ u16t t[64 * 72];
    const int sb = blockIdx.x, h = blockIdx.y, b = blockIdx.z;
    const int tid = threadIdx.x;
#pragma unroll
    for (int it = 0; it < 2; ++it) {
        const int idx = it * 256 + tid;
        const int r = idx >> 3, c8 = idx & 7;
        const u16t* gp = qkv + (size_t)(b * SQL + sb * 64 + r) * (3 * DM) + 2 * DM + h * HDM + c8 * 8;
        *(us8*)&t[r * 72 + c8 * 8] = *(const us8*)gp;
    }
    __syncthreads();
#pragma unroll
    for (int it = 0; it < 2; ++it) {
        const int idx = it * 256 + tid;
        const int d = idx >> 3, s8 = idx & 7;
        us8 o;
#pragma unroll
        for (int u = 0; u < 8; ++u) o[u] = t[(s8 * 8 + u) * 72 + d];
        u16t* gp = vt + (size_t)((b * NHE + h) * HDM + d) * SQL + sb * 64 + s8 * 8;
        *(us8*)gp = o;
    }
}

// ---------------- flash attention: S^T via 16x16x32, PV via 16x16x16 (P in regs) ----
// S^T = K.Q^T : C-layout col = token = l15, row = j = quad*4+r  (per 16-tile)
// O  = P.V    : A = P from sacc registers, B = V^T b64 reads from swizzled Vs.
// Swizzle: logical 16B chunk c of row r lives at physical chunk c ^ (r & 7).
// launch_bounds(256,2): design needs ~110-150 VGPRs; (256,4) caps at 64 -> spill (r3).
__global__ __launch_bounds__(256, 2) void flash_attn(const u16t* __restrict__ qkv,
                                                     const u16t* __restrict__ vtg,
                                                     const float* __restrict__ mask,
                                                     const int* __restrict__ flag,
                                                     u16t* __restrict__ ctx) {
    __shared__ u16t Ks[128 * 64];        // K[j][d], 8 chunks/row, swizzled
    __shared__ u16t Vs[64 * 128];        // V^T[d][j], 16 chunks/row, swizzled

    const int qt = blockIdx.x, h = blockIdx.y, b = blockIdx.z;
    const int tid = threadIdx.x;
    const int w = tid >> 6, lane = tid & 63;
    const int l15 = lane & 15, quad = lane >> 4;
    const int e3 = l15 & 7;
    const bool allones = (*flag != 42);

    // Q fragments (B-operand of S^T: n = token = l15, k = quad*8+j)
    bf16x8 qf[2][2];
#pragma unroll
    for (int mt = 0; mt < 2; ++mt) {
        const size_t rowb = (size_t)(b * SQL + qt * 128 + w * 32 + mt * 16 + l15) * (3 * DM) + h * HDM;
#pragma unroll
        for (int kk = 0; kk < 2; ++kk)
            qf[mt][kk] = *(const bf16x8*)(qkv + rowb + kk * 32 + quad * 8);
    }

    f32x4 oacc[4][2] = {};               // [dt][mt]; row = token quad*4+r, col = d l15
    float m_r[2] = {-3.0e38f, -3.0e38f};
    float l_r[2] = {0.0f, 0.0f};

    const int r8 = lane >> 3, c8 = lane & 7;     // K staging decomposition
    const int r4 = lane >> 4, c16 = lane & 15;   // V staging decomposition

    for (int kt = 0; kt < SQL / 128; ++kt) {
        const int j0 = kt * 128;
        __syncthreads();
#pragma unroll
        for (int i = 0; i < 4; ++i) {            // K-tile: 8 rows x 8 chunks per iter
            const int row = j0 + w * 32 + i * 8 + r8;
            load_lds16(qkv + (size_t)(b * SQL + row) * (3 * DM) + DM + h * HDM + ((c8 ^ r8) * 8),
                       &Ks[(w * 32 + i * 8) * 64]);
        }
#pragma unroll
        for (int i = 0; i < 4; ++i) {            // V^T tile: 4 d-rows x 16 chunks per iter
            const int d = w * 16 + i * 4 + r4;
            load_lds16(vtg + (size_t)((b * NHE + h) * HDM + d) * SQL + j0 + ((c16 ^ ((i * 4 + r4) & 7)) * 8),
                       &Vs[(w * 16 + i * 4) * 128]);
        }
        __syncthreads();

        // S^T = K . Q^T
        f32x4 sacc[2][8] = {};
#pragma unroll
        for (int kk = 0; kk < 2; ++kk) {
#pragma unroll
            for (int jt = 0; jt < 8; ++jt) {
                bf16x8 af = *(const bf16x8*)&Ks[(jt * 16 + l15) * 64 + (((kk * 4 + quad) ^ e3) * 8)];
                sacc[0][jt] = mfma16(af, qf[0][kk], sacc[0][jt]);
                sacc[1][jt] = mfma16(af, qf[1][kk], sacc[1][jt]);
            }
        }

        // online softmax; 1/8 scale and log2(e) folded into the exp2 argument
        float av[2][4];
#pragma unroll
        for (int mt = 0; mt < 2; ++mt) {
            if (!allones) {
                const int gi = qt * 128 + w * 32 + mt * 16 + l15;
#pragma unroll
                for (int jt = 0; jt < 8; ++jt)
#pragma unroll
                    for (int r = 0; r < 4; ++r) {
                        const int gj = j0 + jt * 16 + quad * 4 + r;
                        sacc[mt][jt][r] = sacc[mt][jt][r] * 0.125f
                                        + (1.0f - mask[((size_t)b * SQL + gi) * SQL + gj]) * (-1.0e9f);
                    }
            }
            float mx = -3.0e38f;
#pragma unroll
            for (int jt = 0; jt < 8; ++jt)
#pragma unroll
                for (int r = 0; r < 4; ++r) mx = fmaxf(mx, sacc[mt][jt][r]);
            mx = fmaxf(mx, __shfl_xor(mx, 16));
            mx = fmaxf(mx, __shfl_xor(mx, 32));
            const float cs = allones ? 0.18033688011112042f : 1.4426950408889634f;
            const float mnew = fmaxf(m_r[mt], mx);
            const float mb = mnew * cs;
            const float alpha = ex2(fmaf(m_r[mt], cs, -mb));
            m_r[mt] = mnew;
            float rsum = 0.0f;
#pragma unroll
            for (int jt = 0; jt < 8; ++jt)
#pragma unroll
                for (int r = 0; r < 4; ++r) {
                    const float p = ex2(fmaf(sacc[mt][jt][r], cs, -mb));
                    sacc[mt][jt][r] = p;
                    rsum += p;
                }
            rsum += __shfl_xor(rsum, 16);
            rsum += __shfl_xor(rsum, 32);
            l_r[mt] = l_r[mt] * alpha + rsum;
            // broadcast alpha from softmax lanes (token=l15) to O rows (token=quad*4+r)
#pragma unroll
            for (int r = 0; r < 4; ++r) av[mt][r] = __shfl(alpha, quad * 4 + r);
#pragma unroll
            for (int dt = 0; dt < 4; ++dt)
#pragma unroll
                for (int r = 0; r < 4; ++r) oacc[dt][mt][r] *= av[mt][r];
        }

        // O += P . V  (A = P packed via v_perm, B from Vs)
#pragma unroll
        for (int jt = 0; jt < 8; ++jt) {
            union { s16x4 v; unsigned int u[2]; } pa0, pa1;
            pa0.u[0] = pk_bf2(sacc[0][jt][0], sacc[0][jt][1]);
            pa0.u[1] = pk_bf2(sacc[0][jt][2], sacc[0][jt][3]);
            pa1.u[0] = pk_bf2(sacc[1][jt][0], sacc[1][jt][1]);
            pa1.u[1] = pk_bf2(sacc[1][jt][2], sacc[1][jt][3]);
            const int vcol = (((2 * jt + (quad >> 1)) ^ e3) * 8) + (quad & 1) * 4;
#pragma unroll
            for (int dt = 0; dt < 4; ++dt) {
                s16x4 vb = *(const s16x4*)&Vs[(dt * 16 + l15) * 128 + vcol];
                oacc[dt][0] = mfma16k16(pa0.v, vb, oacc[dt][0]);
                oacc[dt][1] = mfma16k16(pa1.v, vb, oacc[dt][1]);
            }
        }
    }

    // epilogue: broadcast l to O rows, normalize, store
#pragma unroll
    for (int mt = 0; mt < 2; ++mt) {
        float lv[4];
#pragma unroll
        for (int r = 0; r < 4; ++r) lv[r] = __shfl(l_r[mt], quad * 4 + r);
#pragma unroll
        for (int r = 0; r < 4; ++r) {
            const float inv = 1.0f / lv[r];
            const int token = qt * 128 + w * 32 + mt * 16 + quad * 4 + r;
            const size_t base = (size_t)(b * SQL + token) * DM + h * HDM;
#pragma unroll
            for (int dt = 0; dt < 4; ++dt)
                ctx[base + dt * 16 + l15] = f2bf(oacc[dt][mt][r] * inv);
        }
    }
}

// ---------------- fused residual + LayerNorm (one wave per 512-elem row) -----------
template <bool WBF>
__global__ __launch_bounds__(256) void ln_fused(const float* __restrict__ xa,
                                                const float* __restrict__ xb,
                                                const float* __restrict__ g,
                                                const float* __restrict__ be,
                                                float* __restrict__ outf,
                                                u16t* __restrict__ outh) {
    const int row = blockIdx.x * 4 + (threadIdx.x >> 6);
    const int lane = threadIdx.x & 63;
    const size_t base = (size_t)row * DM;
    f32x4 a0 = *(const f32x4*)(xa + base + lane * 4);
    f32x4 b0 = *(const f32x4*)(xb + base + lane * 4);
    f32x4 a1 = *(const f32x4*)(xa + base + 256 + lane * 4);
    f32x4 b1 = *(const f32x4*)(xb + base + 256 + lane * 4);
    f32x4 v0 = a0 + b0, v1 = a1 + b1;
    float s = v0[0] + v0[1] + v0[2] + v0[3] + v1[0] + v1[1] + v1[2] + v1[3];
    float q = v0[0]*v0[0] + v0[1]*v0[1] + v0[2]*v0[2] + v0[3]*v0[3]
            + v1[0]*v1[0] + v1[1]*v1[1] + v1[2]*v1[2] + v1[3]*v1[3];
#pragma unroll
    for (int off = 1; off < 64; off <<= 1) {
        s += __shfl_xor(s, off);
        q += __shfl_xor(q, off);
    }
    const float mean = s * (1.0f / DM);
    const float var = q * (1.0f / DM) - mean * mean;
    const float rs = rsqrtf(var + 1e-5f);
    f32x4 g0 = *(const f32x4*)(g + lane * 4);
    f32x4 g1 = *(const f32x4*)(g + 256 + lane * 4);
    f32x4 e0 = *(const f32x4*)(be + lane * 4);
    f32x4 e1 = *(const f32x4*)(be + 256 + lane * 4);
    f32x4 y0, y1;
#pragma unroll
    for (int i = 0; i < 4; ++i) {
        y0[i] = (v0[i] - mean) * rs * g0[i] + e0[i];
        y1[i] = (v1[i] - mean) * rs * g1[i] + e1[i];
    }
    *(f32x4*)(outf + base + lane * 4) = y0;
    *(f32x4*)(outf + base + 256 + lane * 4) = y1;
    if (WBF) {
        us4 h0, h1;
#pragma unroll
        for (int i = 0; i < 4; ++i) { h0[i] = f2bf(y0[i]); h1[i] = f2bf(y1[i]); }
        *(us4*)(outh + base + lane * 4) = h0;
        *(us4*)(outh + base + 256 + lane * 4) = h1;
    }
}

// ---------------- host ----------------
extern "C" void kernel_launch(void* const* d_in, const int* in_sizes, int n_in,
                              void* d_out, int out_size, void* d_ws, size_t ws_size,
                              hipStream_t stream) {
    const float* src  = (const float*)d_in[0];
    const float* mask = (const float*)d_in[1];
    const float* Wq = (const float*)d_in[2];
    const float* bq = (const float*)d_in[3];
    const float* Wk = (const float*)d_in[4];
    const float* bk = (const float*)d_in[5];
    const float* Wv = (const float*)d_in[6];
    const float* bv = (const float*)d_in[7];
    const float* Wo = (const float*)d_in[8];
    const float* bo = (const float*)d_in[9];
    const float* W1 = (const float*)d_in[10];
    const float* b1 = (const float*)d_in[11];
    const float* W2 = (const float*)d_in[12];
    const float* b2 = (const float*)d_in[13];
    const float* ln1g = (const float*)d_in[14];
    const float* ln1b = (const float*)d_in[15];
    const float* ln2g = (const float*)d_in[16];
    const float* ln2b = (const float*)d_in[17];

    const int M = NB * SQL;  // 8192 tokens

    char* p = (char*)d_ws;
    auto take = [&](size_t bytes) {
        char* r = p;
        p += (bytes + 1023) & ~(size_t)1023;
        return r;
    };
    u16t* regA   = (u16t*)take((size_t)M * DFF * 2);      // qkv [M,1536] then h [M,2048]
    u16t* vtb    = (u16t*)take((size_t)NB * NHE * HDM * SQL * 2);
    u16t* ctxb   = (u16t*)take((size_t)M * DM * 2);
    float* sa_ff = (float*)take((size_t)M * DM * 4);      // sa then ff
    float* x1f   = (float*)take((size_t)M * DM * 4);
    u16t* x1h    = (u16t*)take((size_t)M * DM * 2);
    u16t* srcbf  = (u16t*)take((size_t)M * DM * 2);
    u16t* wqkv   = (u16t*)take((size_t)3 * DM * DM * 2);
    float* bqkv  = (float*)take((size_t)3 * DM * 4);
    u16t* woc    = (u16t*)take((size_t)DM * DM * 2);
    u16t* w1c    = (u16t*)take((size_t)DFF * DM * 2);
    u16t* w2c    = (u16t*)take((size_t)DM * DFF * 2);
    int* flag    = (int*)take(1024);
    u16t* qkvb   = regA;   // [M, 1536]
    u16t* hbuf   = regA;   // [M, 2048] (after flash is done with qkv)

    // converts + bias pack + mask check (order-free flag) in one launch
    convert_all<<<5633, 256, 0, stream>>>(src, Wq, Wk, Wv, Wo, W1, W2, bq, bk, bv,
                                          (const f32x4*)mask,
                                          srcbf, wqkv, woc, w1c, w2c, bqkv, flag);

    // QKV projection: [8192,512] x [1536,512]^T -> [8192,1536] bf16
    gemm_bt<u16t, false, 128><<<dim3(12, 64), 256, 0, stream>>>(srcbf, wqkv, bqkv, qkvb,
                                                                M, 3 * DM, DM, 3 * DM);
    // V transpose for flash B-operand source
    transpose_v<<<dim3(SQL / 64, NHE, NB), 256, 0, stream>>>(qkvb, vtb);
    // attention
    flash_attn<<<dim3(SQL / 128, NHE, NB), 256, 0, stream>>>(qkvb, vtb, mask, flag, ctxb);
    // out projection -> sa (fp32); N=512 narrow -> BN=64, 512 blocks
    gemm_bt<float, false, 64><<<dim3(8, 64), 256, 0, stream>>>(ctxb, woc, bo, sa_ff,
                                                               M, DM, DM, DM);
    // x1 = LN(src + sa)  (fp32 + bf16 copies)
    ln_fused<true><<<M / 4, 256, 0, stream>>>(src, sa_ff, ln1g, ln1b, x1f, x1h);
    // FFN1 + ReLU -> h (bf16)
    gemm_bt<u16t, true, 128><<<dim3(16, 64), 256, 0, stream>>>(x1h, w1c, b1, hbuf,
                                                               M, DFF, DM, DFF);
    // FFN2 -> ff (fp32, reuses sa buffer); N=512 narrow -> BN=64, 512 blocks
    gemm_bt<float, false, 64><<<dim3(8, 64), 256, 0, stream>>>(hbuf, w2c, b2, sa_ff,
                                                               M, DM, DFF, DM);
    // out = LN(x1 + ff)
    ln_fused<false><<<M / 4, 256, 0, stream>>>(x1f, sa_ff, ln2g, ln2b, (float*)d_out,
                                               (u16t*)nullptr);
}